// Round 1
// 164.090 us; speedup vs baseline: 1.0114x; 1.0114x over previous
//
#include <hip/hip_runtime.h>

typedef unsigned long long u64;
typedef unsigned int u32;
typedef short short8 __attribute__((ext_vector_type(8)));
typedef float f32x4 __attribute__((ext_vector_type(4)));
typedef u32 u32x4v __attribute__((ext_vector_type(4)));

#define N_PTS   4096
#define B_SZ    4
#define N_PER_B 1024
#define L_TOK   16
#define FV      256
#define FL      768
#define FDIM    128
#define KNN     16
#define RH      64   // rel_encoder hidden

#define MFMA_BF16(a, b, c) __builtin_amdgcn_mfma_f32_16x16x32_bf16((a), (b), (c), 0, 0, 0)

__device__ __forceinline__ short f2bf(float f) {
    unsigned int x = __float_as_uint(f);
    unsigned int r = (x + 0x7fffu + ((x >> 16) & 1u)) >> 16;
    return (short)r;
}

// =====================================================================
// K1: fused independent work. 256-thread blocks, specialized by range:
//   [0,1024)      knn, 4 queries/block (one wave each)         [unchanged]
//   [1024,1088)   lang encoder stage 1, 1 row/block (split-k 2)[unchanged]
//   [1088,1344)   features -> bf16 hi/lo split, A-frag order
//   [1344,1352)   W1 -> bf16 hi/lo split, B-frag order
//   [1352,1356)   W2 -> bf16 hi/lo split, B-frag order
// The feat encoder GEMMs moved to K2 (MFMA) — they consumed ~half of
// k1's 42 us as scalar-FMA loops with MfmaUtil=0.
// =====================================================================
__global__ __launch_bounds__(256) void k1_kernel(const float* __restrict__ xyz,
                                                 const float* __restrict__ features,
                                                 const float* __restrict__ lf,
                                                 const float* __restrict__ Wl1,
                                                 const float* __restrict__ bl1,
                                                 const float* __restrict__ W1,
                                                 const float* __restrict__ W2,
                                                 int* __restrict__ knn,
                                                 float* __restrict__ hl,
                                                 short* __restrict__ fp_hi,
                                                 short* __restrict__ fp_lo,
                                                 short* __restrict__ w1p_hi,
                                                 short* __restrict__ w1p_lo,
                                                 short* __restrict__ w2p_hi,
                                                 short* __restrict__ w2p_lo) {
    __shared__ float smem[1024];
    int b = blockIdx.x, t = threadIdx.x;

    if (b < 1024) {
        // ---------------- kNN: one wave per query ----------------
        int lane = t & 63;
        int q = b * 4 + (t >> 6);
        int base = (q >> 10) << 10;
        float qx = xyz[q * 3 + 0];
        float qy = xyz[q * 3 + 1];
        float qz = xyz[q * 3 + 2];
        u64 keys[16];
#pragma unroll
        for (int m = 0; m < 16; m++) {
            int j = base + lane + (m << 6);
            float dx = qx - xyz[j * 3 + 0];
            float dy = qy - xyz[j * 3 + 1];
            float dz = qz - xyz[j * 3 + 2];
            // match reference rounding: no fma contraction, (x+y) then +z
            float d2 = __fadd_rn(__fadd_rn(__fmul_rn(dx, dx), __fmul_rn(dy, dy)),
                                 __fmul_rn(dz, dz));
            keys[m] = (((u64)__float_as_uint(d2)) << 32) | (unsigned int)j;
        }
        for (int r = 0; r < KNN; r++) {
            u64 lmin = keys[0];
#pragma unroll
            for (int m = 1; m < 16; m++) lmin = (keys[m] < lmin) ? keys[m] : lmin;
            u64 g = lmin;
#pragma unroll
            for (int off = 32; off > 0; off >>= 1) {
                u64 o = __shfl_xor(g, off, 64);
                g = (o < g) ? o : g;
            }
#pragma unroll
            for (int m = 0; m < 16; m++)
                if (keys[m] == g) keys[m] = ~0ULL;
            if (lane == 0) knn[q * KNN + r] = (int)(g & 0xffffffffu);
        }
    } else if (b < 1088) {
        // ---------------- lang stage 1: hl = lang_row @ Wl1 + bl1 ------
        int r = b - 1024;
        float* lrow = smem;          // [768]
        float* part = smem + 768;    // [2][128]
        for (int k = t; k < FL; k += 256) lrow[k] = lf[r * FL + k];
        __syncthreads();
        int c = t & 127, kh = t >> 7;
        float acc = (kh == 0) ? bl1[c] : 0.f;
        int k0 = kh * 384;
        for (int k = k0; k < k0 + 384; k++) acc += lrow[k] * Wl1[k * FDIM + c];
        part[kh * FDIM + c] = acc;
        __syncthreads();
        if (kh == 0) hl[r * FDIM + c] = part[c] + part[FDIM + c];
    } else if (b < 1344) {
        // ------------- features split-pack: 1 row-tile (16 rows)/block --
        // fp[rt][ks][lane][j] = split(features[rt*16 + (lane&15)]
        //                                      [ks*32 + (lane>>4)*8 + j])
        int rt = b - 1088;
        int lane = t & 63, kh = t >> 6;
        int e = lane & 15, q = lane >> 4;
#pragma unroll
        for (int pp = 0; pp < 2; pp++) {
            int ks = kh * 2 + pp;
            const float* src = features + (rt * 16 + e) * FV + ks * 32 + q * 8;
            float4 f0 = *(const float4*)src;
            float4 f1 = *(const float4*)(src + 4);
            float f[8] = {f0.x, f0.y, f0.z, f0.w, f1.x, f1.y, f1.z, f1.w};
            short8 hi, lo;
#pragma unroll
            for (int j = 0; j < 8; j++) {
                u32 bits = __float_as_uint(f[j]);
                hi[j] = (short)(bits >> 16);
                float lof = f[j] - __uint_as_float(bits & 0xffff0000u);
                lo[j] = (short)(__float_as_uint(lof) >> 16);
            }
            int o = ((rt * 8 + ks) * 64 + lane) * 8;
            *(short8*)(fp_hi + o) = hi;
            *(short8*)(fp_lo + o) = lo;
        }
    } else {
        // ------------- weight split-pack (B-frag order) ----------------
        // wp[ks][ct][lane][j] = split(W[(ks*32 + (lane>>4)*8 + j)*128
        //                               + ct*16 + (lane&15)])
        int isW2 = (b >= 1352);
        int ks = isW2 ? (b - 1352) : (b - 1344);
        const float* W = isW2 ? W2 : W1;
        short* ph = isW2 ? w2p_hi : w1p_hi;
        short* pl = isW2 ? w2p_lo : w1p_lo;
        int lane = t & 63, cth = t >> 6;
        int e = lane & 15, q = lane >> 4;
#pragma unroll
        for (int p = 0; p < 2; p++) {
            int ct = cth * 2 + p;
            short8 hi, lo;
#pragma unroll
            for (int j = 0; j < 8; j++) {
                float w = W[(ks * 32 + q * 8 + j) * FDIM + ct * 16 + e];
                u32 bits = __float_as_uint(w);
                hi[j] = (short)(bits >> 16);
                float lof = w - __uint_as_float(bits & 0xffff0000u);
                lo[j] = (short)(__float_as_uint(lof) >> 16);
            }
            int o = ((ks * 8 + ct) * 64 + lane) * 8;
            *(short8*)(ph + o) = hi;
            *(short8*)(pl + o) = lo;
        }
    }
}

// =====================================================================
// K2: feat encoder via MFMA (blocks [0,64)) + lang stage 2 ([64,80)).
// Feat: 16 rows/wave, 4 waves/block. Split-bf16 3-MFMA per tile gives
// ~fp32 accuracy (dropped lo*lo term ~2^-16 relative).
//   GEMM1: acc[ct] (C: col=ct*16+(lane&15), row=(lane>>4)*4+reg)
//   LN in-register: rows live on (q,reg); 16-lane shfl_xor reduce over e.
//   Transpose via per-wave LDS tile (stride 132 -> 2-way/floor banks),
//   same-wave ds write->read, no barriers.
//   GEMM2: A-frag read back from LDS, packed u32 = (hi16<<16)|lo16.
// =====================================================================
__global__ __launch_bounds__(256) void k2_kernel(const short* __restrict__ fp_hi,
                                                 const short* __restrict__ fp_lo,
                                                 const short* __restrict__ w1p_hi,
                                                 const short* __restrict__ w1p_lo,
                                                 const short* __restrict__ w2p_hi,
                                                 const short* __restrict__ w2p_lo,
                                                 const float* __restrict__ b1,
                                                 const float* __restrict__ ln_g,
                                                 const float* __restrict__ ln_b,
                                                 const float* __restrict__ b2,
                                                 const float* __restrict__ hl,
                                                 const float* __restrict__ bn_g,
                                                 const float* __restrict__ bn_b,
                                                 const float* __restrict__ Wl2,
                                                 const float* __restrict__ bl2,
                                                 float* __restrict__ feats,
                                                 float* __restrict__ lang) {
    int b = blockIdx.x, t = threadIdx.x;
    if (b < 64) {
        __shared__ u32 hbuf[4][16 * 132];
        int wid = t >> 6, lane = t & 63;
        int e = lane & 15, q = lane >> 4;
        int rt = b * 4 + wid;               // rows rt*16 .. rt*16+16

        // ---- GEMM1: h = features @ W1 + b1 ----
        f32x4 acc[8];
#pragma unroll
        for (int ct = 0; ct < 8; ct++) {
            float v = b1[ct * 16 + e];
            acc[ct] = (f32x4){v, v, v, v};
        }
        for (int ks = 0; ks < 8; ks++) {
            int ao = ((rt * 8 + ks) * 64 + lane) * 8;
            short8 ah = *(const short8*)(fp_hi + ao);
            short8 al = *(const short8*)(fp_lo + ao);
#pragma unroll
            for (int ct = 0; ct < 8; ct++) {
                int bo = ((ks * 8 + ct) * 64 + lane) * 8;
                short8 bh = *(const short8*)(w1p_hi + bo);
                short8 bl = *(const short8*)(w1p_lo + bo);
                acc[ct] = MFMA_BF16(ah, bh, acc[ct]);
                acc[ct] = MFMA_BF16(al, bh, acc[ct]);
                acc[ct] = MFMA_BF16(ah, bl, acc[ct]);
            }
        }
        // ---- LayerNorm over 128 cols per row ----
        float s[4], sq[4];
#pragma unroll
        for (int r = 0; r < 4; r++) { s[r] = 0.f; sq[r] = 0.f; }
#pragma unroll
        for (int ct = 0; ct < 8; ct++)
#pragma unroll
            for (int r = 0; r < 4; r++) {
                float v = acc[ct][r];
                s[r] += v; sq[r] += v * v;
            }
#pragma unroll
        for (int off = 1; off < 16; off <<= 1)
#pragma unroll
            for (int r = 0; r < 4; r++) {
                s[r] += __shfl_xor(s[r], off, 16);
                sq[r] += __shfl_xor(sq[r], off, 16);
            }
        float mu[4], rs[4];
#pragma unroll
        for (int r = 0; r < 4; r++) {
            mu[r] = s[r] * (1.f / 128.f);
            float var = sq[r] * (1.f / 128.f) - mu[r] * mu[r];
            rs[r] = rsqrtf(var + 1e-5f);
        }
        // ---- normalize + ReLU + split-pack -> LDS (transpose) ----
        u32* hrow = &hbuf[wid][0];
#pragma unroll
        for (int ct = 0; ct < 8; ct++) {
            float g = ln_g[ct * 16 + e], bb = ln_b[ct * 16 + e];
#pragma unroll
            for (int r = 0; r < 4; r++) {
                float n = fmaxf((acc[ct][r] - mu[r]) * rs[r] * g + bb, 0.f);
                u32 nb = __float_as_uint(n);
                u32 hh = nb & 0xffff0000u;
                float lof = n - __uint_as_float(hh);
                hrow[(q * 4 + r) * 132 + ct * 16 + e] = hh | (__float_as_uint(lof) >> 16);
            }
        }
        // ---- GEMM2: feats = relu(h_norm) @ W2 + b2 ----
        f32x4 acc2[8];
#pragma unroll
        for (int ct = 0; ct < 8; ct++) {
            float v = b2[ct * 16 + e];
            acc2[ct] = (f32x4){v, v, v, v};
        }
#pragma unroll
        for (int ks = 0; ks < 4; ks++) {
            u32 hv[8];
            *(u32x4v*)&hv[0] = *(const u32x4v*)&hrow[e * 132 + ks * 32 + q * 8];
            *(u32x4v*)&hv[4] = *(const u32x4v*)&hrow[e * 132 + ks * 32 + q * 8 + 4];
            short8 ah, al;
#pragma unroll
            for (int j = 0; j < 8; j++) {
                ah[j] = (short)(hv[j] >> 16);
                al[j] = (short)(hv[j] & 0xffffu);
            }
#pragma unroll
            for (int ct = 0; ct < 8; ct++) {
                int bo = ((ks * 8 + ct) * 64 + lane) * 8;
                short8 bh = *(const short8*)(w2p_hi + bo);
                short8 bl = *(const short8*)(w2p_lo + bo);
                acc2[ct] = MFMA_BF16(ah, bh, acc2[ct]);
                acc2[ct] = MFMA_BF16(al, bh, acc2[ct]);
                acc2[ct] = MFMA_BF16(ah, bl, acc2[ct]);
            }
        }
#pragma unroll
        for (int ct = 0; ct < 8; ct++)
#pragma unroll
            for (int r = 0; r < 4; r++)
                feats[(rt * 16 + q * 4 + r) * FDIM + ct * 16 + e] = acc2[ct][r];
    } else {
        // ---- lang stage 2: BN (batch stats) + ReLU + GEMM2, 4 rows/block
        __shared__ float rl4[4][FDIM];
        int tt = t & 127;
        int act = (t < 128);
        int r0 = (b - 64) * 4;
        if (act) {
            float s = 0.f, s2 = 0.f;
            for (int r = 0; r < 64; r++) {
                float v = hl[r * FDIM + tt];
                s += v; s2 += v * v;
            }
            float mu = s * (1.f / 64.f);
            float var = s2 * (1.f / 64.f) - mu * mu;
            float rs = rsqrtf(var + 1e-5f);
            float g = bn_g[tt], bb = bn_b[tt];
#pragma unroll
            for (int p = 0; p < 4; p++)
                rl4[p][tt] = fmaxf((hl[(r0 + p) * FDIM + tt] - mu) * rs * g + bb, 0.f);
        }
        __syncthreads();
        if (act) {
            float bv = bl2[tt];
            float a0 = bv, a1 = bv, a2 = bv, a3 = bv;
            for (int k = 0; k < FDIM; k++) {
                float w = Wl2[k * FDIM + tt];
                a0 += rl4[0][k] * w;
                a1 += rl4[1][k] * w;
                a2 += rl4[2][k] * w;
                a3 += rl4[3][k] * w;
            }
            lang[(r0 + 0) * FDIM + tt] = a0;
            lang[(r0 + 1) * FDIM + tt] = a1;
            lang[(r0 + 2) * FDIM + tt] = a2;
            lang[(r0 + 3) * FDIM + tt] = a3;
        }
    }
}

// =====================================================================
// K3: attention logits atten[i,l] = feats_i · lang[b_i, l]. 2 points/block.
// =====================================================================
__global__ __launch_bounds__(256) void atten_kernel(const float* __restrict__ feats,
                                                    const float* __restrict__ lang,
                                                    float* __restrict__ atten) {
    __shared__ float fb[2][FDIM];
    __shared__ float pb[256];
    int t = threadIdx.x;
    int half = t >> 7, tt = t & 127;
    int i = blockIdx.x * 2 + half;
    fb[half][tt] = feats[i * FDIM + tt];
    __syncthreads();
    int l = tt >> 3, sj = tt & 7;
    int bi = i >> 10;
    const float* lrow = lang + (bi * L_TOK + l) * FDIM;
    float p = 0.f;
#pragma unroll
    for (int m = 0; m < 16; m++) {
        int k = sj + (m << 3);
        p += fb[half][k] * lrow[k];
    }
    pb[t] = p;
    __syncthreads();
    if (tt < L_TOK) {
        float a = 0.f;
#pragma unroll
        for (int u = 0; u < 8; u++) a += pb[half * 128 + tt * 8 + u];
        atten[i * L_TOK + tt] = a;
    }
}

// =====================================================================
// K4: edge kernel v3 — ONE QUERY PER WAVE, zero LDS, zero barriers.
// Softmax via 16-lane shuffle groups; ew (16x64 @ 64x128) and
// ctx (16x16 @ 16x128, K zero-padded to 32) via bf16 MFMA 16x16x32.
// A[m=lane&15][k=quad*8+j]; B[k=quad*8+j][n=lane&15];
// C col=lane&15, row=quad*4+reg.
// =====================================================================
__global__ __launch_bounds__(256) void edge_kernel(const float* __restrict__ xyz,
                                                   const float* __restrict__ mask,
                                                   const float* __restrict__ Wr1,
                                                   const float* __restrict__ br1,
                                                   const float* __restrict__ Wr2,
                                                   const float* __restrict__ br2,
                                                   const int* __restrict__ knn,
                                                   const float* __restrict__ lang,
                                                   const float* __restrict__ feats,
                                                   const float* __restrict__ atten,
                                                   float* __restrict__ out) {
    int lane = threadIdx.x & 63;
    int wid  = threadIdx.x >> 6;
    int i    = blockIdx.x * 4 + wid;          // query
    int bi   = i >> 10;
    int quad = lane >> 4;
    int e16  = lane & 15;

    // neighbor index for e = lane&15 (same across quads)
    int idxe = knn[i * KNN + e16];

    // ---- gather logits: this lane holds l = quad*8 + j (quads 0,1 real) ----
    float sat[8];
    if (quad < 2) {
        const float4* ap = (const float4*)(atten + idxe * L_TOK + quad * 8);
        float4 a0 = ap[0], a1 = ap[1];
        sat[0] = a0.x; sat[1] = a0.y; sat[2] = a0.z; sat[3] = a0.w;
        sat[4] = a1.x; sat[5] = a1.y; sat[6] = a1.z; sat[7] = a1.w;
    } else {
#pragma unroll
        for (int j = 0; j < 8; j++) sat[j] = 0.f;
    }

    // ---- segment softmax over e (16-lane shuffle groups; quads independent)
    float mx[8];
#pragma unroll
    for (int j = 0; j < 8; j++) mx[j] = sat[j];
#pragma unroll
    for (int off = 1; off < 16; off <<= 1) {
#pragma unroll
        for (int j = 0; j < 8; j++) mx[j] = fmaxf(mx[j], __shfl_xor(mx[j], off, 16));
    }
    float ex[8], sm[8];
#pragma unroll
    for (int j = 0; j < 8; j++) { ex[j] = __expf(sat[j] - mx[j]); sm[j] = ex[j]; }
#pragma unroll
    for (int off = 1; off < 16; off <<= 1) {
#pragma unroll
        for (int j = 0; j < 8; j++) sm[j] += __shfl_xor(sm[j], off, 16);
    }
    float st[8];
    if (quad < 2) {
        const float4* mp = (const float4*)(mask + i * L_TOK + quad * 8);
        float4 m0 = mp[0], m1 = mp[1];
        float mv[8] = {m0.x, m0.y, m0.z, m0.w, m1.x, m1.y, m1.z, m1.w};
#pragma unroll
        for (int j = 0; j < 8; j++) st[j] = ex[j] * (mv[j] / sm[j]);
    } else {
#pragma unroll
        for (int j = 0; j < 8; j++) st[j] = 0.f;
    }
    // per-e normalization over l (sum across the two real quads)
    float s = st[0] + st[1] + st[2] + st[3] + st[4] + st[5] + st[6] + st[7];
    s += __shfl_xor(s, 16, 64);
    s += __shfl_xor(s, 32, 64);
    float inv2 = 1.f / (s + 1e-7f);
    short8 sattA;
#pragma unroll
    for (int j = 0; j < 8; j++) sattA[j] = f2bf(st[j] * inv2);

    // ---- rel_encoder hidden layer: hid[e=lane&15][k = s*32+quad*8+j] ----
    float xi0 = xyz[i * 3 + 0], xi1 = xyz[i * 3 + 1], xi2 = xyz[i * 3 + 2];
    float xj0 = xyz[idxe * 3 + 0], xj1 = xyz[idxe * 3 + 1], xj2 = xyz[idxe * 3 + 2];
    float d0 = xi0 - xj0, d1 = xi1 - xj1, d2v = xi2 - xj2;
    float nr = sqrtf(d0 * d0 + d1 * d1 + d2v * d2v + 1e-12f);
    float ein[10] = {xi0, xi1, xi2, xj0, xj1, xj2, d0, d1, d2v, nr};
    short8 hidA[2];
#pragma unroll
    for (int sstep = 0; sstep < 2; sstep++) {
        int k0 = sstep * 32 + quad * 8;
        float h[8];
        const float4* bp = (const float4*)(br1 + k0);
        float4 b0 = bp[0], b1v = bp[1];
        h[0] = b0.x; h[1] = b0.y; h[2] = b0.z; h[3] = b0.w;
        h[4] = b1v.x; h[5] = b1v.y; h[6] = b1v.z; h[7] = b1v.w;
#pragma unroll
        for (int m = 0; m < 10; m++) {
            const float4* wp = (const float4*)(Wr1 + m * RH + k0);
            float4 w0 = wp[0], w1 = wp[1];
            float em = ein[m];
            h[0] += em * w0.x; h[1] += em * w0.y; h[2] += em * w0.z; h[3] += em * w0.w;
            h[4] += em * w1.x; h[5] += em * w1.y; h[6] += em * w1.z; h[7] += em * w1.w;
        }
#pragma unroll
        for (int j = 0; j < 8; j++) hidA[sstep][j] = f2bf(fmaxf(h[j], 0.f));
    }

    // row (e) indices for the C-layout gathers: e = quad*4 + r
    int idxr[4];
#pragma unroll
    for (int r = 0; r < 4; r++) idxr[r] = knn[i * KNN + quad * 4 + r];

    // ---- per c-tile: ew MFMA (2 steps) + ctx MFMA (1 padded step) ----
#pragma unroll 2
    for (int tile = 0; tile < 8; tile++) {
        int cc = tile * 16 + e16;   // this lane's column
        f32x4 accew = {0.f, 0.f, 0.f, 0.f};
#pragma unroll
        for (int sstep = 0; sstep < 2; sstep++) {
            short8 w2B;
#pragma unroll
            for (int j = 0; j < 8; j++)
                w2B[j] = f2bf(Wr2[(sstep * 32 + quad * 8 + j) * FDIM + cc]);
            accew = __builtin_amdgcn_mfma_f32_16x16x32_bf16(hidA[sstep], w2B, accew, 0, 0, 0);
        }
        short8 lsB;
        if (quad < 2) {
#pragma unroll
            for (int j = 0; j < 8; j++)
                lsB[j] = f2bf(lang[bi * L_TOK * FDIM + (quad * 8 + j) * FDIM + cc]);
        } else {
#pragma unroll
            for (int j = 0; j < 8; j++) lsB[j] = 0;
        }
        f32x4 accctx = {0.f, 0.f, 0.f, 0.f};
        accctx = __builtin_amdgcn_mfma_f32_16x16x32_bf16(sattA, lsB, accctx, 0, 0, 0);

        float br2c = br2[cc];
        float msum = 0.f;
#pragma unroll
        for (int r = 0; r < 4; r++) {
            float fj = feats[idxr[r] * FDIM + cc];
            msum += fj * accctx[r] * (accew[r] + br2c);
        }
        msum += __shfl_xor(msum, 16, 64);
        msum += __shfl_xor(msum, 32, 64);
        if (lane < 16)
            out[i * FDIM + cc] = feats[i * FDIM + cc] + msum;
    }
}

extern "C" void kernel_launch(void* const* d_in, const int* in_sizes, int n_in,
                              void* d_out, int out_size, void* d_ws, size_t ws_size,
                              hipStream_t stream) {
    const float* xyz   = (const float*)d_in[0];
    // d_in[1] = batch_index (int32) — layout-implied (i>>10), unused
    const float* features = (const float*)d_in[2];
    const float* lang_f   = (const float*)d_in[3];
    const float* mask     = (const float*)d_in[4];
    const float* W1   = (const float*)d_in[5];
    const float* b1   = (const float*)d_in[6];
    const float* ln_g = (const float*)d_in[7];
    const float* ln_b = (const float*)d_in[8];
    const float* W2   = (const float*)d_in[9];
    const float* b2   = (const float*)d_in[10];
    const float* Wl1  = (const float*)d_in[11];
    const float* bl1  = (const float*)d_in[12];
    const float* bn_g = (const float*)d_in[13];
    const float* bn_b = (const float*)d_in[14];
    const float* Wl2  = (const float*)d_in[15];
    const float* bl2  = (const float*)d_in[16];
    const float* Wr1  = (const float*)d_in[17];
    const float* br1  = (const float*)d_in[18];
    const float* Wr2  = (const float*)d_in[19];
    const float* br2  = (const float*)d_in[20];

    float* ws_feats = (float*)d_ws;                       // N*F
    float* ws_atten = ws_feats + N_PTS * FDIM;            // N*L
    float* ws_lang  = ws_atten + N_PTS * L_TOK;           // B*L*F
    float* ws_hl    = ws_lang + B_SZ * L_TOK * FDIM;      // 64*F
    int*   ws_knn   = (int*)(ws_hl + 64 * FDIM);          // N*K
    short* fp_hi    = (short*)(ws_knn + N_PTS * KNN);     // N*FV bf16
    short* fp_lo    = fp_hi + N_PTS * FV;                 // N*FV bf16
    short* w1p_hi   = fp_lo + N_PTS * FV;                 // FV*F
    short* w1p_lo   = w1p_hi + FV * FDIM;
    short* w2p_hi   = w1p_lo + FV * FDIM;                 // F*F
    short* w2p_lo   = w2p_hi + FDIM * FDIM;

    k1_kernel<<<1356, 256, 0, stream>>>(xyz, features, lang_f, Wl1, bl1, W1, W2,
                                        ws_knn, ws_hl,
                                        fp_hi, fp_lo, w1p_hi, w1p_lo, w2p_hi, w2p_lo);
    k2_kernel<<<80, 256, 0, stream>>>(fp_hi, fp_lo, w1p_hi, w1p_lo, w2p_hi, w2p_lo,
                                      b1, ln_g, ln_b, b2,
                                      ws_hl, bn_g, bn_b, Wl2, bl2,
                                      ws_feats, ws_lang);
    atten_kernel<<<N_PTS / 2, 256, 0, stream>>>(ws_feats, ws_lang, ws_atten);
    edge_kernel<<<N_PTS / 4, 256, 0, stream>>>(xyz, mask, Wr1, br1, Wr2, br2,
                                               ws_knn, ws_lang, ws_feats, ws_atten,
                                               (float*)d_out);
}

// Round 2
// 156.080 us; speedup vs baseline: 1.0633x; 1.0513x over previous
//
#include <hip/hip_runtime.h>

typedef unsigned long long u64;
typedef unsigned int u32;
typedef short short8 __attribute__((ext_vector_type(8)));
typedef float f32x4 __attribute__((ext_vector_type(4)));
typedef u32 u32x4v __attribute__((ext_vector_type(4)));

#define N_PTS   4096
#define B_SZ    4
#define N_PER_B 1024
#define L_TOK   16
#define FV      256
#define FL      768
#define FDIM    128
#define KNN     16
#define RH      64   // rel_encoder hidden

#define MFMA_BF16(a, b, c) __builtin_amdgcn_mfma_f32_16x16x32_bf16((a), (b), (c), 0, 0, 0)

__device__ __forceinline__ short f2bf(float f) {
    unsigned int x = __float_as_uint(f);
    unsigned int r = (x + 0x7fffu + ((x >> 16) & 1u)) >> 16;
    return (short)r;
}

// =====================================================================
// K1: fused independent work. 256-thread blocks, specialized by range:
//   [0,1024)      knn, 4 queries/block — bitonic sort-merge top-16
//   [1024,1088)   lang encoder stage 1, 1 row/block (split-k 2)
//   [1088,1344)   features -> bf16 hi/lo split, A-frag order
//   [1344,1352)   W1 -> bf16 hi/lo split, B-frag order
//   [1352,1356)   W2 -> bf16 hi/lo split, B-frag order
//   [1356,1358)   Wr2 -> bf16 (f2bf) B-frag pack for edge kernel
// kNN redesign: key = (double)d2_bits*1024 + j_local (exact in f64;
// positive-float bit order == value order; low 10 bits = index tie-break
// identical to jax top_k). Per-lane bitonic sort of 16 (f64 min/max CEs,
// no shuffles), then 6 lane-merge levels keeping lowest-16:
// min(a[i], b[15-i]) + 4-stage in-register bitonic cleanup. Dependency
// depth ~15x shorter than the old 16-round extract loop (which was the
// 40us critical path of the whole pipeline).
// =====================================================================
__global__ __launch_bounds__(256) void k1_kernel(const float* __restrict__ xyz,
                                                 const float* __restrict__ features,
                                                 const float* __restrict__ lf,
                                                 const float* __restrict__ Wl1,
                                                 const float* __restrict__ bl1,
                                                 const float* __restrict__ W1,
                                                 const float* __restrict__ W2,
                                                 const float* __restrict__ Wr2,
                                                 int* __restrict__ knn,
                                                 float* __restrict__ hl,
                                                 short* __restrict__ fp_hi,
                                                 short* __restrict__ fp_lo,
                                                 short* __restrict__ w1p_hi,
                                                 short* __restrict__ w1p_lo,
                                                 short* __restrict__ w2p_hi,
                                                 short* __restrict__ w2p_lo,
                                                 short* __restrict__ w2pe) {
    __shared__ float smem[1024];
    int b = blockIdx.x, t = threadIdx.x;

    if (b < 1024) {
        // ---------------- kNN: one wave per query ----------------
        int lane = t & 63;
        int q = b * 4 + (t >> 6);
        int base = (q >> 10) << 10;
        float qx = xyz[q * 3 + 0];
        float qy = xyz[q * 3 + 1];
        float qz = xyz[q * 3 + 2];
        double key[16];
#pragma unroll
        for (int m = 0; m < 16; m++) {
            int jl = lane + (m << 6);          // local index, 10 bits
            int j = base + jl;
            float dx = qx - xyz[j * 3 + 0];
            float dy = qy - xyz[j * 3 + 1];
            float dz = qz - xyz[j * 3 + 2];
            // match reference rounding: no fma contraction, (x+y) then +z
            float d2 = __fadd_rn(__fadd_rn(__fmul_rn(dx, dx), __fmul_rn(dy, dy)),
                                 __fmul_rn(dz, dz));
            key[m] = (double)__float_as_uint(d2) * 1024.0 + (double)jl;
        }
        // per-lane bitonic sort, ascending (80 CEs, f64 min/max = 2 instr)
#pragma unroll
        for (int k = 2; k <= 16; k <<= 1) {
#pragma unroll
            for (int jj = k >> 1; jj > 0; jj >>= 1) {
#pragma unroll
                for (int i = 0; i < 16; i++) {
                    int l = i ^ jj;
                    if (l > i) {
                        double lo = fmin(key[i], key[l]);
                        double hi = fmax(key[i], key[l]);
                        bool asc = ((i & k) == 0);
                        key[i] = asc ? lo : hi;
                        key[l] = asc ? hi : lo;
                    }
                }
            }
        }
        // 6 merge levels over lanes: keep lowest-16 of (mine ∪ partner)
#pragma unroll
        for (int lvl = 1; lvl <= 32; lvl <<= 1) {
            double pk[16];
#pragma unroll
            for (int i = 0; i < 16; i++) pk[i] = __shfl_xor(key[15 - i], lvl, 64);
#pragma unroll
            for (int i = 0; i < 16; i++) key[i] = fmin(key[i], pk[i]);
            // bitonic cleanup: sort the bitonic lowest-16 ascending
#pragma unroll
            for (int jj = 8; jj > 0; jj >>= 1) {
#pragma unroll
                for (int i = 0; i < 16; i++) {
                    int l = i ^ jj;
                    if (l > i) {
                        double lo = fmin(key[i], key[l]);
                        double hi = fmax(key[i], key[l]);
                        key[i] = lo;
                        key[l] = hi;
                    }
                }
            }
        }
        if (lane == 0) {
            int idx[16];
#pragma unroll
            for (int i = 0; i < 16; i++)
                idx[i] = base + (int)(((u64)key[i]) & 1023u);
#pragma unroll
            for (int w = 0; w < 4; w++) {
                int4 v = {idx[4 * w], idx[4 * w + 1], idx[4 * w + 2], idx[4 * w + 3]};
                *(int4*)&knn[q * KNN + 4 * w] = v;
            }
        }
    } else if (b < 1088) {
        // ---------------- lang stage 1: hl = lang_row @ Wl1 + bl1 ------
        int r = b - 1024;
        float* lrow = smem;          // [768]
        float* part = smem + 768;    // [2][128]
        for (int k = t; k < FL; k += 256) lrow[k] = lf[r * FL + k];
        __syncthreads();
        int c = t & 127, kh = t >> 7;
        float acc = (kh == 0) ? bl1[c] : 0.f;
        int k0 = kh * 384;
        for (int k = k0; k < k0 + 384; k++) acc += lrow[k] * Wl1[k * FDIM + c];
        part[kh * FDIM + c] = acc;
        __syncthreads();
        if (kh == 0) hl[r * FDIM + c] = part[c] + part[FDIM + c];
    } else if (b < 1344) {
        // ------------- features split-pack: 1 row-tile (16 rows)/block --
        int rt = b - 1088;
        int lane = t & 63, kh = t >> 6;
        int e = lane & 15, q = lane >> 4;
#pragma unroll
        for (int pp = 0; pp < 2; pp++) {
            int ks = kh * 2 + pp;
            const float* src = features + (rt * 16 + e) * FV + ks * 32 + q * 8;
            float4 f0 = *(const float4*)src;
            float4 f1 = *(const float4*)(src + 4);
            float f[8] = {f0.x, f0.y, f0.z, f0.w, f1.x, f1.y, f1.z, f1.w};
            short8 hi, lo;
#pragma unroll
            for (int j = 0; j < 8; j++) {
                u32 bits = __float_as_uint(f[j]);
                hi[j] = (short)(bits >> 16);
                float lof = f[j] - __uint_as_float(bits & 0xffff0000u);
                lo[j] = (short)(__float_as_uint(lof) >> 16);
            }
            int o = ((rt * 8 + ks) * 64 + lane) * 8;
            *(short8*)(fp_hi + o) = hi;
            *(short8*)(fp_lo + o) = lo;
        }
    } else if (b < 1356) {
        // ------------- weight split-pack (B-frag order) ----------------
        int isW2 = (b >= 1352);
        int ks = isW2 ? (b - 1352) : (b - 1344);
        const float* W = isW2 ? W2 : W1;
        short* ph = isW2 ? w2p_hi : w1p_hi;
        short* pl = isW2 ? w2p_lo : w1p_lo;
        int lane = t & 63, cth = t >> 6;
        int e = lane & 15, q = lane >> 4;
#pragma unroll
        for (int p = 0; p < 2; p++) {
            int ct = cth * 2 + p;
            short8 hi, lo;
#pragma unroll
            for (int j = 0; j < 8; j++) {
                float w = W[(ks * 32 + q * 8 + j) * FDIM + ct * 16 + e];
                u32 bits = __float_as_uint(w);
                hi[j] = (short)(bits >> 16);
                float lof = w - __uint_as_float(bits & 0xffff0000u);
                lo[j] = (short)(__float_as_uint(lof) >> 16);
            }
            int o = ((ks * 8 + ct) * 64 + lane) * 8;
            *(short8*)(ph + o) = hi;
            *(short8*)(pl + o) = lo;
        }
    } else {
        // ------------- Wr2 bf16 pack (f2bf round), B-frag order --------
        int ks = b - 1356;           // 0..1 (K = 64)
        int lane = t & 63, cth = t >> 6;
        int e = lane & 15, q = lane >> 4;
#pragma unroll
        for (int p = 0; p < 2; p++) {
            int ct = cth * 2 + p;
            short8 v;
#pragma unroll
            for (int j = 0; j < 8; j++)
                v[j] = f2bf(Wr2[(ks * 32 + q * 8 + j) * FDIM + ct * 16 + e]);
            *(short8*)(w2pe + ((ks * 8 + ct) * 64 + lane) * 8) = v;
        }
    }
}

// =====================================================================
// K2: feat encoder via MFMA (blocks [0,64)) + lang stage 2 ([64,80)).
// =====================================================================
__global__ __launch_bounds__(256) void k2_kernel(const short* __restrict__ fp_hi,
                                                 const short* __restrict__ fp_lo,
                                                 const short* __restrict__ w1p_hi,
                                                 const short* __restrict__ w1p_lo,
                                                 const short* __restrict__ w2p_hi,
                                                 const short* __restrict__ w2p_lo,
                                                 const float* __restrict__ b1,
                                                 const float* __restrict__ ln_g,
                                                 const float* __restrict__ ln_b,
                                                 const float* __restrict__ b2,
                                                 const float* __restrict__ hl,
                                                 const float* __restrict__ bn_g,
                                                 const float* __restrict__ bn_b,
                                                 const float* __restrict__ Wl2,
                                                 const float* __restrict__ bl2,
                                                 float* __restrict__ feats,
                                                 float* __restrict__ lang) {
    int b = blockIdx.x, t = threadIdx.x;
    if (b < 64) {
        __shared__ u32 hbuf[4][16 * 132];
        int wid = t >> 6, lane = t & 63;
        int e = lane & 15, q = lane >> 4;
        int rt = b * 4 + wid;               // rows rt*16 .. rt*16+16

        // ---- GEMM1: h = features @ W1 + b1 ----
        f32x4 acc[8];
#pragma unroll
        for (int ct = 0; ct < 8; ct++) {
            float v = b1[ct * 16 + e];
            acc[ct] = (f32x4){v, v, v, v};
        }
        for (int ks = 0; ks < 8; ks++) {
            int ao = ((rt * 8 + ks) * 64 + lane) * 8;
            short8 ah = *(const short8*)(fp_hi + ao);
            short8 al = *(const short8*)(fp_lo + ao);
#pragma unroll
            for (int ct = 0; ct < 8; ct++) {
                int bo = ((ks * 8 + ct) * 64 + lane) * 8;
                short8 bh = *(const short8*)(w1p_hi + bo);
                short8 bl = *(const short8*)(w1p_lo + bo);
                acc[ct] = MFMA_BF16(ah, bh, acc[ct]);
                acc[ct] = MFMA_BF16(al, bh, acc[ct]);
                acc[ct] = MFMA_BF16(ah, bl, acc[ct]);
            }
        }
        // ---- LayerNorm over 128 cols per row ----
        float s[4], sq[4];
#pragma unroll
        for (int r = 0; r < 4; r++) { s[r] = 0.f; sq[r] = 0.f; }
#pragma unroll
        for (int ct = 0; ct < 8; ct++)
#pragma unroll
            for (int r = 0; r < 4; r++) {
                float v = acc[ct][r];
                s[r] += v; sq[r] += v * v;
            }
#pragma unroll
        for (int off = 1; off < 16; off <<= 1)
#pragma unroll
            for (int r = 0; r < 4; r++) {
                s[r] += __shfl_xor(s[r], off, 16);
                sq[r] += __shfl_xor(sq[r], off, 16);
            }
        float mu[4], rs[4];
#pragma unroll
        for (int r = 0; r < 4; r++) {
            mu[r] = s[r] * (1.f / 128.f);
            float var = sq[r] * (1.f / 128.f) - mu[r] * mu[r];
            rs[r] = rsqrtf(var + 1e-5f);
        }
        // ---- normalize + ReLU + split-pack -> LDS (transpose) ----
        u32* hrow = &hbuf[wid][0];
#pragma unroll
        for (int ct = 0; ct < 8; ct++) {
            float g = ln_g[ct * 16 + e], bb = ln_b[ct * 16 + e];
#pragma unroll
            for (int r = 0; r < 4; r++) {
                float n = fmaxf((acc[ct][r] - mu[r]) * rs[r] * g + bb, 0.f);
                u32 nb = __float_as_uint(n);
                u32 hh = nb & 0xffff0000u;
                float lof = n - __uint_as_float(hh);
                hrow[(q * 4 + r) * 132 + ct * 16 + e] = hh | (__float_as_uint(lof) >> 16);
            }
        }
        // ---- GEMM2: feats = relu(h_norm) @ W2 + b2 ----
        f32x4 acc2[8];
#pragma unroll
        for (int ct = 0; ct < 8; ct++) {
            float v = b2[ct * 16 + e];
            acc2[ct] = (f32x4){v, v, v, v};
        }
#pragma unroll
        for (int ks = 0; ks < 4; ks++) {
            u32 hv[8];
            *(u32x4v*)&hv[0] = *(const u32x4v*)&hrow[e * 132 + ks * 32 + q * 8];
            *(u32x4v*)&hv[4] = *(const u32x4v*)&hrow[e * 132 + ks * 32 + q * 8 + 4];
            short8 ah, al;
#pragma unroll
            for (int j = 0; j < 8; j++) {
                ah[j] = (short)(hv[j] >> 16);
                al[j] = (short)(hv[j] & 0xffffu);
            }
#pragma unroll
            for (int ct = 0; ct < 8; ct++) {
                int bo = ((ks * 8 + ct) * 64 + lane) * 8;
                short8 bh = *(const short8*)(w2p_hi + bo);
                short8 bl = *(const short8*)(w2p_lo + bo);
                acc2[ct] = MFMA_BF16(ah, bh, acc2[ct]);
                acc2[ct] = MFMA_BF16(al, bh, acc2[ct]);
                acc2[ct] = MFMA_BF16(ah, bl, acc2[ct]);
            }
        }
#pragma unroll
        for (int ct = 0; ct < 8; ct++)
#pragma unroll
            for (int r = 0; r < 4; r++)
                feats[(rt * 16 + q * 4 + r) * FDIM + ct * 16 + e] = acc2[ct][r];
    } else {
        // ---- lang stage 2: BN (batch stats) + ReLU + GEMM2, 4 rows/block
        __shared__ float rl4[4][FDIM];
        int tt = t & 127;
        int act = (t < 128);
        int r0 = (b - 64) * 4;
        if (act) {
            float s = 0.f, s2 = 0.f;
            for (int r = 0; r < 64; r++) {
                float v = hl[r * FDIM + tt];
                s += v; s2 += v * v;
            }
            float mu = s * (1.f / 64.f);
            float var = s2 * (1.f / 64.f) - mu * mu;
            float rs = rsqrtf(var + 1e-5f);
            float g = bn_g[tt], bb = bn_b[tt];
#pragma unroll
            for (int p = 0; p < 4; p++)
                rl4[p][tt] = fmaxf((hl[(r0 + p) * FDIM + tt] - mu) * rs * g + bb, 0.f);
        }
        __syncthreads();
        if (act) {
            float bv = bl2[tt];
            float a0 = bv, a1 = bv, a2 = bv, a3 = bv;
            for (int k = 0; k < FDIM; k++) {
                float w = Wl2[k * FDIM + tt];
                a0 += rl4[0][k] * w;
                a1 += rl4[1][k] * w;
                a2 += rl4[2][k] * w;
                a3 += rl4[3][k] * w;
            }
            lang[(r0 + 0) * FDIM + tt] = a0;
            lang[(r0 + 1) * FDIM + tt] = a1;
            lang[(r0 + 2) * FDIM + tt] = a2;
            lang[(r0 + 3) * FDIM + tt] = a3;
        }
    }
}

// =====================================================================
// K3: attention logits ([0,2048)) + lang bf16 B-frag pack ([2048,2052)).
// =====================================================================
__global__ __launch_bounds__(256) void atten_kernel(const float* __restrict__ feats,
                                                    const float* __restrict__ lang,
                                                    float* __restrict__ atten,
                                                    short* __restrict__ langp) {
    int t = threadIdx.x;
    int b = blockIdx.x;
    if (b < 2048) {
        __shared__ float fb[2][FDIM];
        __shared__ float pb[256];
        int half = t >> 7, tt = t & 127;
        int i = b * 2 + half;
        fb[half][tt] = feats[i * FDIM + tt];
        __syncthreads();
        int l = tt >> 3, sj = tt & 7;
        int bi = i >> 10;
        const float* lrow = lang + (bi * L_TOK + l) * FDIM;
        float p = 0.f;
#pragma unroll
        for (int m = 0; m < 16; m++) {
            int k = sj + (m << 3);
            p += fb[half][k] * lrow[k];
        }
        pb[t] = p;
        __syncthreads();
        if (tt < L_TOK) {
            float a = 0.f;
#pragma unroll
            for (int u = 0; u < 8; u++) a += pb[half * 128 + tt * 8 + u];
            atten[i * L_TOK + tt] = a;
        }
    } else {
        // pack lang -> bf16 B-frag layout for the edge kernel's ctx MFMA
        int bi = b - 2048;
        int lane = t & 63, w = t >> 6;
        int e = lane & 15, qd = lane >> 4;
#pragma unroll
        for (int p = 0; p < 2; p++) {
            int tile = w * 2 + p;
            short8 v;
            if (qd < 2) {
#pragma unroll
                for (int j = 0; j < 8; j++)
                    v[j] = f2bf(lang[bi * L_TOK * FDIM + (qd * 8 + j) * FDIM + tile * 16 + e]);
            } else {
#pragma unroll
                for (int j = 0; j < 8; j++) v[j] = 0;
            }
            *(short8*)(langp + ((bi * 8 + tile) * 64 + lane) * 8) = v;
        }
    }
}

// =====================================================================
// K4: edge kernel — ONE QUERY PER WAVE, zero LDS, zero barriers.
// Wr2 and lang now arrive pre-packed in bf16 B-frag order (w2pe/langp):
// the inner tile loop is 2 coalesced 16B loads + 3 MFMAs instead of
// 24 scalar loads + 24 f2bf per tile.
// =====================================================================
__global__ __launch_bounds__(256) void edge_kernel(const float* __restrict__ xyz,
                                                   const float* __restrict__ mask,
                                                   const float* __restrict__ Wr1,
                                                   const float* __restrict__ br1,
                                                   const float* __restrict__ br2,
                                                   const int* __restrict__ knn,
                                                   const short* __restrict__ w2pe,
                                                   const short* __restrict__ langp,
                                                   const float* __restrict__ feats,
                                                   const float* __restrict__ atten,
                                                   float* __restrict__ out) {
    int lane = threadIdx.x & 63;
    int wid  = threadIdx.x >> 6;
    int i    = blockIdx.x * 4 + wid;          // query
    int bi   = i >> 10;
    int quad = lane >> 4;
    int e16  = lane & 15;

    // neighbor index for e = lane&15 (same across quads)
    int idxe = knn[i * KNN + e16];

    // ---- gather logits: this lane holds l = quad*8 + j (quads 0,1 real) ----
    float sat[8];
    if (quad < 2) {
        const float4* ap = (const float4*)(atten + idxe * L_TOK + quad * 8);
        float4 a0 = ap[0], a1 = ap[1];
        sat[0] = a0.x; sat[1] = a0.y; sat[2] = a0.z; sat[3] = a0.w;
        sat[4] = a1.x; sat[5] = a1.y; sat[6] = a1.z; sat[7] = a1.w;
    } else {
#pragma unroll
        for (int j = 0; j < 8; j++) sat[j] = 0.f;
    }

    // ---- segment softmax over e (16-lane shuffle groups; quads independent)
    float mx[8];
#pragma unroll
    for (int j = 0; j < 8; j++) mx[j] = sat[j];
#pragma unroll
    for (int off = 1; off < 16; off <<= 1) {
#pragma unroll
        for (int j = 0; j < 8; j++) mx[j] = fmaxf(mx[j], __shfl_xor(mx[j], off, 16));
    }
    float ex[8], sm[8];
#pragma unroll
    for (int j = 0; j < 8; j++) { ex[j] = __expf(sat[j] - mx[j]); sm[j] = ex[j]; }
#pragma unroll
    for (int off = 1; off < 16; off <<= 1) {
#pragma unroll
        for (int j = 0; j < 8; j++) sm[j] += __shfl_xor(sm[j], off, 16);
    }
    float st[8];
    if (quad < 2) {
        const float4* mp = (const float4*)(mask + i * L_TOK + quad * 8);
        float4 m0 = mp[0], m1 = mp[1];
        float mv[8] = {m0.x, m0.y, m0.z, m0.w, m1.x, m1.y, m1.z, m1.w};
#pragma unroll
        for (int j = 0; j < 8; j++) st[j] = ex[j] * (mv[j] / sm[j]);
    } else {
#pragma unroll
        for (int j = 0; j < 8; j++) st[j] = 0.f;
    }
    // per-e normalization over l (sum across the two real quads)
    float s = st[0] + st[1] + st[2] + st[3] + st[4] + st[5] + st[6] + st[7];
    s += __shfl_xor(s, 16, 64);
    s += __shfl_xor(s, 32, 64);
    float inv2 = 1.f / (s + 1e-7f);
    short8 sattA;
#pragma unroll
    for (int j = 0; j < 8; j++) sattA[j] = f2bf(st[j] * inv2);

    // ---- rel_encoder hidden layer: hid[e=lane&15][k = s*32+quad*8+j] ----
    float xi0 = xyz[i * 3 + 0], xi1 = xyz[i * 3 + 1], xi2 = xyz[i * 3 + 2];
    float xj0 = xyz[idxe * 3 + 0], xj1 = xyz[idxe * 3 + 1], xj2 = xyz[idxe * 3 + 2];
    float d0 = xi0 - xj0, d1 = xi1 - xj1, d2v = xi2 - xj2;
    float nr = sqrtf(d0 * d0 + d1 * d1 + d2v * d2v + 1e-12f);
    float ein[10] = {xi0, xi1, xi2, xj0, xj1, xj2, d0, d1, d2v, nr};
    short8 hidA[2];
#pragma unroll
    for (int sstep = 0; sstep < 2; sstep++) {
        int k0 = sstep * 32 + quad * 8;
        float h[8];
        const float4* bp = (const float4*)(br1 + k0);
        float4 b0 = bp[0], b1v = bp[1];
        h[0] = b0.x; h[1] = b0.y; h[2] = b0.z; h[3] = b0.w;
        h[4] = b1v.x; h[5] = b1v.y; h[6] = b1v.z; h[7] = b1v.w;
#pragma unroll
        for (int m = 0; m < 10; m++) {
            const float4* wp = (const float4*)(Wr1 + m * RH + k0);
            float4 w0 = wp[0], w1 = wp[1];
            float em = ein[m];
            h[0] += em * w0.x; h[1] += em * w0.y; h[2] += em * w0.z; h[3] += em * w0.w;
            h[4] += em * w1.x; h[5] += em * w1.y; h[6] += em * w1.z; h[7] += em * w1.w;
        }
#pragma unroll
        for (int j = 0; j < 8; j++) hidA[sstep][j] = f2bf(fmaxf(h[j], 0.f));
    }

    // row (e) indices for the C-layout gathers: e = quad*4 + r
    int idxr[4];
#pragma unroll
    for (int r = 0; r < 4; r++) idxr[r] = knn[i * KNN + quad * 4 + r];

    // ---- per c-tile: ew MFMA (2 steps) + ctx MFMA (1 padded step) ----
#pragma unroll 2
    for (int tile = 0; tile < 8; tile++) {
        int cc = tile * 16 + e16;   // this lane's column
        f32x4 accew = {0.f, 0.f, 0.f, 0.f};
#pragma unroll
        for (int sstep = 0; sstep < 2; sstep++) {
            short8 w2B = *(const short8*)(w2pe + ((sstep * 8 + tile) * 64 + lane) * 8);
            accew = __builtin_amdgcn_mfma_f32_16x16x32_bf16(hidA[sstep], w2B, accew, 0, 0, 0);
        }
        short8 lsB = *(const short8*)(langp + ((bi * 8 + tile) * 64 + lane) * 8);
        f32x4 accctx = {0.f, 0.f, 0.f, 0.f};
        accctx = __builtin_amdgcn_mfma_f32_16x16x32_bf16(sattA, lsB, accctx, 0, 0, 0);

        float br2c = br2[cc];
        float msum = 0.f;
#pragma unroll
        for (int r = 0; r < 4; r++) {
            float fj = feats[idxr[r] * FDIM + cc];
            msum += fj * accctx[r] * (accew[r] + br2c);
        }
        msum += __shfl_xor(msum, 16, 64);
        msum += __shfl_xor(msum, 32, 64);
        if (lane < 16)
            out[i * FDIM + cc] = feats[i * FDIM + cc] + msum;
    }
}

extern "C" void kernel_launch(void* const* d_in, const int* in_sizes, int n_in,
                              void* d_out, int out_size, void* d_ws, size_t ws_size,
                              hipStream_t stream) {
    const float* xyz   = (const float*)d_in[0];
    // d_in[1] = batch_index (int32) — layout-implied (i>>10), unused
    const float* features = (const float*)d_in[2];
    const float* lang_f   = (const float*)d_in[3];
    const float* mask     = (const float*)d_in[4];
    const float* W1   = (const float*)d_in[5];
    const float* b1   = (const float*)d_in[6];
    const float* ln_g = (const float*)d_in[7];
    const float* ln_b = (const float*)d_in[8];
    const float* W2   = (const float*)d_in[9];
    const float* b2   = (const float*)d_in[10];
    const float* Wl1  = (const float*)d_in[11];
    const float* bl1  = (const float*)d_in[12];
    const float* bn_g = (const float*)d_in[13];
    const float* bn_b = (const float*)d_in[14];
    const float* Wl2  = (const float*)d_in[15];
    const float* bl2  = (const float*)d_in[16];
    const float* Wr1  = (const float*)d_in[17];
    const float* br1  = (const float*)d_in[18];
    const float* Wr2  = (const float*)d_in[19];
    const float* br2  = (const float*)d_in[20];

    float* ws_feats = (float*)d_ws;                       // N*F
    float* ws_atten = ws_feats + N_PTS * FDIM;            // N*L
    float* ws_lang  = ws_atten + N_PTS * L_TOK;           // B*L*F
    float* ws_hl    = ws_lang + B_SZ * L_TOK * FDIM;      // 64*F
    int*   ws_knn   = (int*)(ws_hl + 64 * FDIM);          // N*K
    short* fp_hi    = (short*)(ws_knn + N_PTS * KNN);     // N*FV bf16
    short* fp_lo    = fp_hi + N_PTS * FV;                 // N*FV bf16
    short* w1p_hi   = fp_lo + N_PTS * FV;                 // FV*F
    short* w1p_lo   = w1p_hi + FV * FDIM;
    short* w2p_hi   = w1p_lo + FV * FDIM;                 // F*F
    short* w2p_lo   = w2p_hi + FDIM * FDIM;
    short* w2pe     = w2p_lo + FDIM * FDIM;               // RH*F bf16 (f2bf)
    short* langp    = w2pe + RH * FDIM;                   // B*8*64*8 bf16

    k1_kernel<<<1358, 256, 0, stream>>>(xyz, features, lang_f, Wl1, bl1, W1, W2, Wr2,
                                        ws_knn, ws_hl,
                                        fp_hi, fp_lo, w1p_hi, w1p_lo, w2p_hi, w2p_lo,
                                        w2pe);
    k2_kernel<<<80, 256, 0, stream>>>(fp_hi, fp_lo, w1p_hi, w1p_lo, w2p_hi, w2p_lo,
                                      b1, ln_g, ln_b, b2,
                                      ws_hl, bn_g, bn_b, Wl2, bl2,
                                      ws_feats, ws_lang);
    atten_kernel<<<2052, 256, 0, stream>>>(ws_feats, ws_lang, ws_atten, langp);
    edge_kernel<<<N_PTS / 4, 256, 0, stream>>>(xyz, mask, Wr1, br1, br2,
                                               ws_knn, w2pe, langp, ws_feats, ws_atten,
                                               (float*)d_out);
}